// Round 2
// baseline (1961.501 us; speedup 1.0000x reference)
//
#include <hip/hip_runtime.h>

#define N_NODES 100000
#define N_EDGES 600000
#define EPS_BN 1e-5f
#define EPS_NORM 1e-12f

// ---------------------------------------------------------------------------
// Degree count + reciprocal
// ---------------------------------------------------------------------------
__global__ void k_count(const int* __restrict__ dst, float* __restrict__ cnt, int E) {
    int e = blockIdx.x * blockDim.x + threadIdx.x;
    if (e < E) atomicAdd(&cnt[dst[e]], 1.0f);
}

__global__ void k_inv(float* __restrict__ cnt, int n) {
    int i = blockIdx.x * blockDim.x + threadIdx.x;
    if (i < n) cnt[i] = 1.0f / fmaxf(cnt[i], 1.0f);
}

// ---------------------------------------------------------------------------
// Scalar scatter (layer 1, D=10)
// ---------------------------------------------------------------------------
template <int D>
__global__ void k_scatter(const float* __restrict__ h, const int* __restrict__ src,
                          const int* __restrict__ dst, float* __restrict__ agg, int E) {
    int tid = blockIdx.x * blockDim.x + threadIdx.x;
    if (tid >= E * D) return;
    int e = tid / D;
    int d = tid - e * D;
    atomicAdd(&agg[(size_t)dst[e] * D + d], h[(size_t)src[e] * D + d]);
}

// ---------------------------------------------------------------------------
// Vectorized scatter: thread per (edge, 4-channel group). float4 read,
// 4 atomics to consecutive addresses (coalesce within a cache line).
// ---------------------------------------------------------------------------
template <int D>
__global__ void k_scatter4(const float* __restrict__ h, const int* __restrict__ src,
                           const int* __restrict__ dst, float* __restrict__ agg, int E) {
    int tid = blockIdx.x * blockDim.x + threadIdx.x;
    constexpr int Q = D / 4;
    int e = tid / Q;
    int q = tid - e * Q;
    if (e >= E) return;
    int s = src[e];
    int d = dst[e];
    float4 v = *(const float4*)&h[(size_t)s * D + q * 4];
    float* o = &agg[(size_t)d * D + q * 4];
    atomicAdd(o + 0, v.x);
    atomicAdd(o + 1, v.y);
    atomicAdd(o + 2, v.z);
    atomicAdd(o + 3, v.w);
}

// ---------------------------------------------------------------------------
// Simple linear (layer 1: DIN=10, DOUT=64) — cheap, keep thread-per-(node,c).
// ---------------------------------------------------------------------------
template <int DIN, int DOUT, bool RELU>
__global__ void k_linear(const float* __restrict__ h, const float* __restrict__ agg,
                         const float* __restrict__ inv_cnt,
                         const float* __restrict__ Wl, const float* __restrict__ Wr,
                         const float* __restrict__ bias,
                         const float* __restrict__ bn_g, const float* __restrict__ bn_b,
                         const float* __restrict__ bn_m, const float* __restrict__ bn_v,
                         float* __restrict__ out, int n) {
    int tid = blockIdx.x * blockDim.x + threadIdx.x;
    int node = tid / DOUT;
    int c = tid - node * DOUT;
    if (node >= n) return;

    float inv = inv_cnt[node];
    const float* hr = h + (size_t)node * DIN;
    const float* ar = agg + (size_t)node * DIN;

    float acc = bias[c];
#pragma unroll
    for (int k = 0; k < DIN; ++k) {
        acc += (ar[k] * inv) * Wl[k * DOUT + c] + hr[k] * Wr[k * DOUT + c];
    }
    float o = (acc - bn_m[c]) * rsqrtf(bn_v[c] + EPS_BN) * bn_g[c] + bn_b[c];
    if (RELU) o = fmaxf(o, 0.0f);
    out[(size_t)node * DOUT + c] = o;
}

// ---------------------------------------------------------------------------
// Register-tiled linear+BN(+ReLU), DOUT=128 only.
// Block: 64 nodes x 128 c; 256 threads = 16 c-groups(8c) x 16 node-groups(4n).
// LDS tile stores interleaved (mean, h) so one ds_read_b64 feeds both FMAs.
// Each weight float4 is reused across 4 nodes -> 16x less L1 weight traffic.
// ---------------------------------------------------------------------------
template <int DIN, bool RELU>
__global__ __launch_bounds__(256) void k_linear_tiled(
    const float* __restrict__ h, const float* __restrict__ agg,
    const float* __restrict__ inv_cnt,
    const float* __restrict__ Wl, const float* __restrict__ Wr,
    const float* __restrict__ bias,
    const float* __restrict__ bn_g, const float* __restrict__ bn_b,
    const float* __restrict__ bn_m, const float* __restrict__ bn_v,
    float* __restrict__ out, int n) {
    constexpr int DOUT = 128;
    __shared__ float2 tile[64][DIN];  // (mean, h) interleaved

    const int tid = threadIdx.x;
    const int node0 = blockIdx.x * 64;

    // ---- stage 64 node rows: tile[nd][k] = {agg[k]*inv, h[k]} ----
#pragma unroll
    for (int it = 0; it < (64 * DIN / 4) / 256; ++it) {
        int qid = it * 256 + tid;
        int nd = qid / (DIN / 4);
        int kq = qid - nd * (DIN / 4);
        int gn = node0 + nd;
        if (gn > n - 1) gn = n - 1;  // clamp: safe reads, results discarded
        float inv = inv_cnt[gn];
        float4 hv = *(const float4*)&h[(size_t)gn * DIN + kq * 4];
        float4 av = *(const float4*)&agg[(size_t)gn * DIN + kq * 4];
        float4 t0 = {av.x * inv, hv.x, av.y * inv, hv.y};
        float4 t1 = {av.z * inv, hv.z, av.w * inv, hv.w};
        float4* dst = (float4*)&tile[nd][kq * 4];
        dst[0] = t0;
        dst[1] = t1;
    }
    __syncthreads();

    const int cgrp = tid & 15;   // 16 c-groups of 8 channels
    const int ngrp = tid >> 4;   // 16 node-groups of 4 nodes
    const int c0 = cgrp * 8;
    const int nbase = ngrp * 4;

    float acc[4][8];
#pragma unroll
    for (int nn = 0; nn < 4; ++nn)
#pragma unroll
        for (int j = 0; j < 8; ++j) acc[nn][j] = 0.0f;

#pragma unroll 4
    for (int k = 0; k < DIN; ++k) {
        float4 wl0 = *(const float4*)&Wl[k * DOUT + c0];
        float4 wl1 = *(const float4*)&Wl[k * DOUT + c0 + 4];
        float4 wr0 = *(const float4*)&Wr[k * DOUT + c0];
        float4 wr1 = *(const float4*)&Wr[k * DOUT + c0 + 4];
#pragma unroll
        for (int nn = 0; nn < 4; ++nn) {
            float2 mh = tile[nbase + nn][k];
            acc[nn][0] = fmaf(mh.x, wl0.x, fmaf(mh.y, wr0.x, acc[nn][0]));
            acc[nn][1] = fmaf(mh.x, wl0.y, fmaf(mh.y, wr0.y, acc[nn][1]));
            acc[nn][2] = fmaf(mh.x, wl0.z, fmaf(mh.y, wr0.z, acc[nn][2]));
            acc[nn][3] = fmaf(mh.x, wl0.w, fmaf(mh.y, wr0.w, acc[nn][3]));
            acc[nn][4] = fmaf(mh.x, wl1.x, fmaf(mh.y, wr1.x, acc[nn][4]));
            acc[nn][5] = fmaf(mh.x, wl1.y, fmaf(mh.y, wr1.y, acc[nn][5]));
            acc[nn][6] = fmaf(mh.x, wl1.z, fmaf(mh.y, wr1.z, acc[nn][6]));
            acc[nn][7] = fmaf(mh.x, wl1.w, fmaf(mh.y, wr1.w, acc[nn][7]));
        }
    }

    // ---- epilogue: BN(+ReLU), folded ----
    float A[8], C[8];
#pragma unroll
    for (int j = 0; j < 8; ++j) {
        int c = c0 + j;
        float a = bn_g[c] * rsqrtf(bn_v[c] + EPS_BN);
        A[j] = a;
        C[j] = (bias[c] - bn_m[c]) * a + bn_b[c];
    }
#pragma unroll
    for (int nn = 0; nn < 4; ++nn) {
        int gn = node0 + nbase + nn;
        if (gn >= n) continue;
        float4 o0, o1;
        o0.x = acc[nn][0] * A[0] + C[0];
        o0.y = acc[nn][1] * A[1] + C[1];
        o0.z = acc[nn][2] * A[2] + C[2];
        o0.w = acc[nn][3] * A[3] + C[3];
        o1.x = acc[nn][4] * A[4] + C[4];
        o1.y = acc[nn][5] * A[5] + C[5];
        o1.z = acc[nn][6] * A[6] + C[6];
        o1.w = acc[nn][7] * A[7] + C[7];
        if (RELU) {
            o0.x = fmaxf(o0.x, 0.0f); o0.y = fmaxf(o0.y, 0.0f);
            o0.z = fmaxf(o0.z, 0.0f); o0.w = fmaxf(o0.w, 0.0f);
            o1.x = fmaxf(o1.x, 0.0f); o1.y = fmaxf(o1.y, 0.0f);
            o1.z = fmaxf(o1.z, 0.0f); o1.w = fmaxf(o1.w, 0.0f);
        }
        *(float4*)&out[(size_t)gn * DOUT + c0] = o0;
        *(float4*)&out[(size_t)gn * DOUT + c0 + 4] = o1;
    }
}

// ---------------------------------------------------------------------------
// L2-normalize + logits (one wave per node)
// ---------------------------------------------------------------------------
__global__ void k_norm_logits(float* __restrict__ emb, float* __restrict__ logits,
                              const float* __restrict__ Wc, const float* __restrict__ bc,
                              int n) {
    int gtid = blockIdx.x * blockDim.x + threadIdx.x;
    int node = gtid >> 6;
    int lane = threadIdx.x & 63;
    if (node >= n) return;

    float* row = emb + (size_t)node * 128;
    float a = row[lane];
    float b = row[lane + 64];

    float ss = a * a + b * b;
#pragma unroll
    for (int off = 32; off; off >>= 1) ss += __shfl_down(ss, off, 64);
    ss = __shfl(ss, 0, 64);

    float inv = 1.0f / fmaxf(sqrtf(ss), EPS_NORM);
    a *= inv;
    b *= inv;
    row[lane] = a;
    row[lane + 64] = b;

    float l0 = a * Wc[lane * 2 + 0] + b * Wc[(lane + 64) * 2 + 0];
    float l1 = a * Wc[lane * 2 + 1] + b * Wc[(lane + 64) * 2 + 1];
#pragma unroll
    for (int off = 32; off; off >>= 1) {
        l0 += __shfl_down(l0, off, 64);
        l1 += __shfl_down(l1, off, 64);
    }
    if (lane == 0) {
        logits[(size_t)node * 2 + 0] = l0 + bc[0];
        logits[(size_t)node * 2 + 1] = l1 + bc[1];
    }
}

// ---------------------------------------------------------------------------
extern "C" void kernel_launch(void* const* d_in, const int* in_sizes, int n_in,
                              void* d_out, int out_size, void* d_ws, size_t ws_size,
                              hipStream_t stream) {
    const float* x    = (const float*)d_in[0];
    const int*   ei   = (const int*)d_in[1];
    const int*   src  = ei;
    const int*   dstp = ei + N_EDGES;

    const float* W1l = (const float*)d_in[2];
    const float* W1r = (const float*)d_in[3];
    const float* b1  = (const float*)d_in[4];
    const float* g1  = (const float*)d_in[5];
    const float* bb1 = (const float*)d_in[6];
    const float* m1  = (const float*)d_in[7];
    const float* v1  = (const float*)d_in[8];

    const float* W2l = (const float*)d_in[9];
    const float* W2r = (const float*)d_in[10];
    const float* b2  = (const float*)d_in[11];
    const float* g2  = (const float*)d_in[12];
    const float* bb2 = (const float*)d_in[13];
    const float* m2  = (const float*)d_in[14];
    const float* v2  = (const float*)d_in[15];

    const float* W3l = (const float*)d_in[16];
    const float* W3r = (const float*)d_in[17];
    const float* b3  = (const float*)d_in[18];
    const float* g3  = (const float*)d_in[19];
    const float* bb3 = (const float*)d_in[20];
    const float* m3  = (const float*)d_in[21];
    const float* v3  = (const float*)d_in[22];

    const float* Wc = (const float*)d_in[23];
    const float* bc = (const float*)d_in[24];

    float* ws  = (float*)d_ws;
    float* cnt = ws;                                  // N (becomes inv_cnt)
    float* agg = cnt + N_NODES;                       // N*128
    float* h1  = agg + (size_t)N_NODES * 128;         // N*64
    float* h2  = h1 + (size_t)N_NODES * 64;           // N*128

    float* emb    = (float*)d_out;
    float* logits = emb + (size_t)N_NODES * 128;

    const int B = 256;
    const int nTileBlocks = (N_NODES + 63) / 64;

    hipMemsetAsync(cnt, 0, N_NODES * sizeof(float), stream);
    k_count<<<(N_EDGES + B - 1) / B, B, 0, stream>>>(dstp, cnt, N_EDGES);
    k_inv<<<(N_NODES + B - 1) / B, B, 0, stream>>>(cnt, N_NODES);

    // ---- layer 1: 10 -> 64, ReLU ----
    hipMemsetAsync(agg, 0, (size_t)N_NODES * 10 * sizeof(float), stream);
    k_scatter<10><<<(N_EDGES * 10 + B - 1) / B, B, 0, stream>>>(x, src, dstp, agg, N_EDGES);
    k_linear<10, 64, true><<<((size_t)N_NODES * 64 + B - 1) / B, B, 0, stream>>>(
        x, agg, cnt, W1l, W1r, b1, g1, bb1, m1, v1, h1, N_NODES);

    // ---- layer 2: 64 -> 128, ReLU ----
    hipMemsetAsync(agg, 0, (size_t)N_NODES * 64 * sizeof(float), stream);
    k_scatter4<64><<<((size_t)N_EDGES * 16 + B - 1) / B, B, 0, stream>>>(h1, src, dstp, agg, N_EDGES);
    k_linear_tiled<64, true><<<nTileBlocks, 256, 0, stream>>>(
        h1, agg, cnt, W2l, W2r, b2, g2, bb2, m2, v2, h2, N_NODES);

    // ---- layer 3: 128 -> 128, no ReLU, into d_out emb region ----
    hipMemsetAsync(agg, 0, (size_t)N_NODES * 128 * sizeof(float), stream);
    k_scatter4<128><<<((size_t)N_EDGES * 32 + B - 1) / B, B, 0, stream>>>(h2, src, dstp, agg, N_EDGES);
    k_linear_tiled<128, false><<<nTileBlocks, 256, 0, stream>>>(
        h2, agg, cnt, W3l, W3r, b3, g3, bb3, m3, v3, emb, N_NODES);

    // ---- normalize + logits ----
    k_norm_logits<<<((size_t)N_NODES * 64 + B - 1) / B, B, 0, stream>>>(emb, logits, Wc, bc, N_NODES);
}

// Round 3
// 634.242 us; speedup vs baseline: 3.0927x; 3.0927x over previous
//
#include <hip/hip_runtime.h>

#define N_NODES 100000
#define N_EDGES 600000
#define EPS_BN 1e-5f
#define EPS_NORM 1e-12f

// ===========================================================================
// CSR build: degree histogram -> exclusive scan -> cursor fill
// ===========================================================================
__global__ void k_deg(const int* __restrict__ dst, int* __restrict__ deg, int E) {
    int e = blockIdx.x * blockDim.x + threadIdx.x;
    if (e < E) atomicAdd(&deg[dst[e]], 1);
}

// per-256-block exclusive scan, emit block sums
__global__ void k_scan1(const int* __restrict__ in, int* __restrict__ out,
                        int* __restrict__ bsum, int n) {
    __shared__ int s[256];
    int i = blockIdx.x * 256 + threadIdx.x;
    int v = (i < n) ? in[i] : 0;
    s[threadIdx.x] = v;
    __syncthreads();
#pragma unroll
    for (int off = 1; off < 256; off <<= 1) {
        int t = (threadIdx.x >= off) ? s[threadIdx.x - off] : 0;
        __syncthreads();
        s[threadIdx.x] += t;
        __syncthreads();
    }
    if (i < n) out[i] = s[threadIdx.x] - v;
    if (threadIdx.x == 255) bsum[blockIdx.x] = s[255];
}

// single-block exclusive scan of block sums (nb <= 512)
__global__ void k_scan2(int* __restrict__ bsum, int nb) {
    __shared__ int s[512];
    int v = (threadIdx.x < nb) ? bsum[threadIdx.x] : 0;
    s[threadIdx.x] = v;
    __syncthreads();
#pragma unroll
    for (int off = 1; off < 512; off <<= 1) {
        int t = (threadIdx.x >= off) ? s[threadIdx.x - off] : 0;
        __syncthreads();
        s[threadIdx.x] += t;
        __syncthreads();
    }
    if (threadIdx.x < nb) bsum[threadIdx.x] = s[threadIdx.x] - v;
}

// add block offsets; init cursor; inv count; offs[n]=E
__global__ void k_prep(int* __restrict__ offs, const int* __restrict__ bsum,
                       const int* __restrict__ deg, int* __restrict__ cursor,
                       float* __restrict__ inv, int n, int E) {
    int i = blockIdx.x * 256 + threadIdx.x;
    if (i >= n) return;
    int o = offs[i] + bsum[i >> 8];
    offs[i] = o;
    cursor[i] = o;
    inv[i] = 1.0f / fmaxf((float)deg[i], 1.0f);
    if (i == 0) offs[n] = E;
}

__global__ void k_fill(const int* __restrict__ src, const int* __restrict__ dst,
                       int* __restrict__ cursor, int* __restrict__ adj, int E) {
    int e = blockIdx.x * blockDim.x + threadIdx.x;
    if (e < E) {
        int pos = atomicAdd(&cursor[dst[e]], 1);
        adj[pos] = src[e];
    }
}

// ===========================================================================
// Gather-aggregate (mean): one 64-lane wave per node, lanes own channels.
// Neighbor rows are contiguous -> coalesced 256B segments per load.
// ===========================================================================
template <int D>
__global__ void k_gather(const float* __restrict__ h, const int* __restrict__ adj,
                         const int* __restrict__ offs, const float* __restrict__ inv,
                         float* __restrict__ mean, int n) {
    int node = (blockIdx.x * blockDim.x + threadIdx.x) >> 6;
    int lane = threadIdx.x & 63;
    if (node >= n) return;
    int beg = offs[node];
    int end = offs[node + 1];
    float iv = inv[node];
    constexpr int J = (D + 63) / 64;
    float acc[J];
#pragma unroll
    for (int j = 0; j < J; ++j) acc[j] = 0.0f;
    for (int p = beg; p < end; ++p) {
        int s = adj[p];  // wave-uniform -> broadcast
        const float* row = h + (size_t)s * D;
#pragma unroll
        for (int j = 0; j < J; ++j) {
            int c = lane + j * 64;
            if (D % 64 == 0 || c < D) acc[j] += row[c];
        }
    }
#pragma unroll
    for (int j = 0; j < J; ++j) {
        int c = lane + j * 64;
        if (D % 64 == 0 || c < D) mean[(size_t)node * D + c] = acc[j] * iv;
    }
}

// ===========================================================================
// Simple linear (layer 1: DIN=10, DOUT=64). mean already divided.
// ===========================================================================
template <int DIN, int DOUT, bool RELU>
__global__ void k_linear(const float* __restrict__ h, const float* __restrict__ mean,
                         const float* __restrict__ Wl, const float* __restrict__ Wr,
                         const float* __restrict__ bias,
                         const float* __restrict__ bn_g, const float* __restrict__ bn_b,
                         const float* __restrict__ bn_m, const float* __restrict__ bn_v,
                         float* __restrict__ out, int n) {
    int tid = blockIdx.x * blockDim.x + threadIdx.x;
    int node = tid / DOUT;
    int c = tid - node * DOUT;
    if (node >= n) return;

    const float* hr = h + (size_t)node * DIN;
    const float* mr = mean + (size_t)node * DIN;

    float acc = bias[c];
#pragma unroll
    for (int k = 0; k < DIN; ++k) {
        acc += mr[k] * Wl[k * DOUT + c] + hr[k] * Wr[k * DOUT + c];
    }
    float o = (acc - bn_m[c]) * rsqrtf(bn_v[c] + EPS_BN) * bn_g[c] + bn_b[c];
    if (RELU) o = fmaxf(o, 0.0f);
    out[(size_t)node * DOUT + c] = o;
}

// ===========================================================================
// Register-tiled linear+BN(+ReLU), DOUT=128. Block: 64 nodes x 128 c.
// ===========================================================================
template <int DIN, bool RELU>
__global__ __launch_bounds__(256) void k_linear_tiled(
    const float* __restrict__ h, const float* __restrict__ mean,
    const float* __restrict__ Wl, const float* __restrict__ Wr,
    const float* __restrict__ bias,
    const float* __restrict__ bn_g, const float* __restrict__ bn_b,
    const float* __restrict__ bn_m, const float* __restrict__ bn_v,
    float* __restrict__ out, int n) {
    constexpr int DOUT = 128;
    __shared__ float2 tile[64][DIN];  // (mean, h) interleaved

    const int tid = threadIdx.x;
    const int node0 = blockIdx.x * 64;

#pragma unroll
    for (int it = 0; it < (64 * DIN / 4) / 256; ++it) {
        int qid = it * 256 + tid;
        int nd = qid / (DIN / 4);
        int kq = qid - nd * (DIN / 4);
        int gn = node0 + nd;
        if (gn > n - 1) gn = n - 1;  // clamp: safe reads, results discarded
        float4 hv = *(const float4*)&h[(size_t)gn * DIN + kq * 4];
        float4 mv = *(const float4*)&mean[(size_t)gn * DIN + kq * 4];
        float4 t0 = {mv.x, hv.x, mv.y, hv.y};
        float4 t1 = {mv.z, hv.z, mv.w, hv.w};
        float4* dstp = (float4*)&tile[nd][kq * 4];
        dstp[0] = t0;
        dstp[1] = t1;
    }
    __syncthreads();

    const int cgrp = tid & 15;
    const int ngrp = tid >> 4;
    const int c0 = cgrp * 8;
    const int nbase = ngrp * 4;

    float acc[4][8];
#pragma unroll
    for (int nn = 0; nn < 4; ++nn)
#pragma unroll
        for (int j = 0; j < 8; ++j) acc[nn][j] = 0.0f;

#pragma unroll 4
    for (int k = 0; k < DIN; ++k) {
        float4 wl0 = *(const float4*)&Wl[k * DOUT + c0];
        float4 wl1 = *(const float4*)&Wl[k * DOUT + c0 + 4];
        float4 wr0 = *(const float4*)&Wr[k * DOUT + c0];
        float4 wr1 = *(const float4*)&Wr[k * DOUT + c0 + 4];
#pragma unroll
        for (int nn = 0; nn < 4; ++nn) {
            float2 mh = tile[nbase + nn][k];
            acc[nn][0] = fmaf(mh.x, wl0.x, fmaf(mh.y, wr0.x, acc[nn][0]));
            acc[nn][1] = fmaf(mh.x, wl0.y, fmaf(mh.y, wr0.y, acc[nn][1]));
            acc[nn][2] = fmaf(mh.x, wl0.z, fmaf(mh.y, wr0.z, acc[nn][2]));
            acc[nn][3] = fmaf(mh.x, wl0.w, fmaf(mh.y, wr0.w, acc[nn][3]));
            acc[nn][4] = fmaf(mh.x, wl1.x, fmaf(mh.y, wr1.x, acc[nn][4]));
            acc[nn][5] = fmaf(mh.x, wl1.y, fmaf(mh.y, wr1.y, acc[nn][5]));
            acc[nn][6] = fmaf(mh.x, wl1.z, fmaf(mh.y, wr1.z, acc[nn][6]));
            acc[nn][7] = fmaf(mh.x, wl1.w, fmaf(mh.y, wr1.w, acc[nn][7]));
        }
    }

    float A[8], C[8];
#pragma unroll
    for (int j = 0; j < 8; ++j) {
        int c = c0 + j;
        float a = bn_g[c] * rsqrtf(bn_v[c] + EPS_BN);
        A[j] = a;
        C[j] = (bias[c] - bn_m[c]) * a + bn_b[c];
    }
#pragma unroll
    for (int nn = 0; nn < 4; ++nn) {
        int gn = node0 + nbase + nn;
        if (gn >= n) continue;
        float4 o0, o1;
        o0.x = acc[nn][0] * A[0] + C[0];
        o0.y = acc[nn][1] * A[1] + C[1];
        o0.z = acc[nn][2] * A[2] + C[2];
        o0.w = acc[nn][3] * A[3] + C[3];
        o1.x = acc[nn][4] * A[4] + C[4];
        o1.y = acc[nn][5] * A[5] + C[5];
        o1.z = acc[nn][6] * A[6] + C[6];
        o1.w = acc[nn][7] * A[7] + C[7];
        if (RELU) {
            o0.x = fmaxf(o0.x, 0.0f); o0.y = fmaxf(o0.y, 0.0f);
            o0.z = fmaxf(o0.z, 0.0f); o0.w = fmaxf(o0.w, 0.0f);
            o1.x = fmaxf(o1.x, 0.0f); o1.y = fmaxf(o1.y, 0.0f);
            o1.z = fmaxf(o1.z, 0.0f); o1.w = fmaxf(o1.w, 0.0f);
        }
        *(float4*)&out[(size_t)gn * DOUT + c0] = o0;
        *(float4*)&out[(size_t)gn * DOUT + c0 + 4] = o1;
    }
}

// ===========================================================================
// L2-normalize + logits (one wave per node)
// ===========================================================================
__global__ void k_norm_logits(float* __restrict__ emb, float* __restrict__ logits,
                              const float* __restrict__ Wc, const float* __restrict__ bc,
                              int n) {
    int gtid = blockIdx.x * blockDim.x + threadIdx.x;
    int node = gtid >> 6;
    int lane = threadIdx.x & 63;
    if (node >= n) return;

    float* row = emb + (size_t)node * 128;
    float a = row[lane];
    float b = row[lane + 64];

    float ss = a * a + b * b;
#pragma unroll
    for (int off = 32; off; off >>= 1) ss += __shfl_down(ss, off, 64);
    ss = __shfl(ss, 0, 64);

    float inv = 1.0f / fmaxf(sqrtf(ss), EPS_NORM);
    a *= inv;
    b *= inv;
    row[lane] = a;
    row[lane + 64] = b;

    float l0 = a * Wc[lane * 2 + 0] + b * Wc[(lane + 64) * 2 + 0];
    float l1 = a * Wc[lane * 2 + 1] + b * Wc[(lane + 64) * 2 + 1];
#pragma unroll
    for (int off = 32; off; off >>= 1) {
        l0 += __shfl_down(l0, off, 64);
        l1 += __shfl_down(l1, off, 64);
    }
    if (lane == 0) {
        logits[(size_t)node * 2 + 0] = l0 + bc[0];
        logits[(size_t)node * 2 + 1] = l1 + bc[1];
    }
}

// ===========================================================================
extern "C" void kernel_launch(void* const* d_in, const int* in_sizes, int n_in,
                              void* d_out, int out_size, void* d_ws, size_t ws_size,
                              hipStream_t stream) {
    const float* x    = (const float*)d_in[0];
    const int*   ei   = (const int*)d_in[1];
    const int*   src  = ei;
    const int*   dstp = ei + N_EDGES;

    const float* W1l = (const float*)d_in[2];
    const float* W1r = (const float*)d_in[3];
    const float* b1  = (const float*)d_in[4];
    const float* g1  = (const float*)d_in[5];
    const float* bb1 = (const float*)d_in[6];
    const float* m1  = (const float*)d_in[7];
    const float* v1  = (const float*)d_in[8];

    const float* W2l = (const float*)d_in[9];
    const float* W2r = (const float*)d_in[10];
    const float* b2  = (const float*)d_in[11];
    const float* g2  = (const float*)d_in[12];
    const float* bb2 = (const float*)d_in[13];
    const float* m2  = (const float*)d_in[14];
    const float* v2  = (const float*)d_in[15];

    const float* W3l = (const float*)d_in[16];
    const float* W3r = (const float*)d_in[17];
    const float* b3  = (const float*)d_in[18];
    const float* g3  = (const float*)d_in[19];
    const float* bb3 = (const float*)d_in[20];
    const float* m3  = (const float*)d_in[21];
    const float* v3  = (const float*)d_in[22];

    const float* Wc = (const float*)d_in[23];
    const float* bc = (const float*)d_in[24];

    // workspace layout (all 4-byte elements)
    float* inv   = (float*)d_ws;                        // N
    int*   deg   = (int*)(inv + N_NODES);               // N
    int*   offs  = deg + N_NODES;                       // N+1
    int*   cursor= offs + N_NODES + 1;                  // N
    int*   adj   = cursor + N_NODES;                    // E
    int*   bsum  = adj + N_EDGES;                       // 512
    float* agg   = (float*)(bsum + 512);                // N*128 (mean buffer)
    float* h1    = agg + (size_t)N_NODES * 128;         // N*64
    float* h2    = h1 + (size_t)N_NODES * 64;           // N*128

    float* emb    = (float*)d_out;
    float* logits = emb + (size_t)N_NODES * 128;

    const int B = 256;
    const int nb = (N_NODES + 255) / 256;               // 391 <= 512
    const int nTileBlocks = (N_NODES + 63) / 64;
    const int nWaveBlocks = ((size_t)N_NODES * 64 + B - 1) / B;

    // ---- CSR build ----
    hipMemsetAsync(deg, 0, N_NODES * sizeof(int), stream);
    k_deg<<<(N_EDGES + B - 1) / B, B, 0, stream>>>(dstp, deg, N_EDGES);
    k_scan1<<<nb, 256, 0, stream>>>(deg, offs, bsum, N_NODES);
    k_scan2<<<1, 512, 0, stream>>>(bsum, nb);
    k_prep<<<nb, 256, 0, stream>>>(offs, bsum, deg, cursor, inv, N_NODES, N_EDGES);
    k_fill<<<(N_EDGES + B - 1) / B, B, 0, stream>>>(src, dstp, cursor, adj, N_EDGES);

    // ---- layer 1: 10 -> 64, ReLU ----
    k_gather<10><<<nWaveBlocks, B, 0, stream>>>(x, adj, offs, inv, agg, N_NODES);
    k_linear<10, 64, true><<<((size_t)N_NODES * 64 + B - 1) / B, B, 0, stream>>>(
        x, agg, W1l, W1r, b1, g1, bb1, m1, v1, h1, N_NODES);

    // ---- layer 2: 64 -> 128, ReLU ----
    k_gather<64><<<nWaveBlocks, B, 0, stream>>>(h1, adj, offs, inv, agg, N_NODES);
    k_linear_tiled<64, true><<<nTileBlocks, 256, 0, stream>>>(
        h1, agg, W2l, W2r, b2, g2, bb2, m2, v2, h2, N_NODES);

    // ---- layer 3: 128 -> 128, no ReLU, into d_out emb region ----
    k_gather<128><<<nWaveBlocks, B, 0, stream>>>(h2, adj, offs, inv, agg, N_NODES);
    k_linear_tiled<128, false><<<nTileBlocks, 256, 0, stream>>>(
        h2, agg, W3l, W3r, b3, g3, bb3, m3, v3, emb, N_NODES);

    // ---- normalize + logits ----
    k_norm_logits<<<nWaveBlocks, B, 0, stream>>>(emb, logits, Wc, bc, N_NODES);
}

// Round 4
// 628.941 us; speedup vs baseline: 3.1187x; 1.0084x over previous
//
#include <hip/hip_runtime.h>

#define N_NODES 100000
#define N_EDGES 600000
#define EPS_BN 1e-5f
#define EPS_NORM 1e-12f

// ===========================================================================
// CSR build: degree histogram -> exclusive scan -> cursor fill
// ===========================================================================
__global__ void k_deg(const int* __restrict__ dst, int* __restrict__ deg, int E) {
    int e = blockIdx.x * blockDim.x + threadIdx.x;
    if (e < E) atomicAdd(&deg[dst[e]], 1);
}

__global__ void k_scan1(const int* __restrict__ in, int* __restrict__ out,
                        int* __restrict__ bsum, int n) {
    __shared__ int s[256];
    int i = blockIdx.x * 256 + threadIdx.x;
    int v = (i < n) ? in[i] : 0;
    s[threadIdx.x] = v;
    __syncthreads();
#pragma unroll
    for (int off = 1; off < 256; off <<= 1) {
        int t = (threadIdx.x >= off) ? s[threadIdx.x - off] : 0;
        __syncthreads();
        s[threadIdx.x] += t;
        __syncthreads();
    }
    if (i < n) out[i] = s[threadIdx.x] - v;
    if (threadIdx.x == 255) bsum[blockIdx.x] = s[255];
}

__global__ void k_scan2(int* __restrict__ bsum, int nb) {
    __shared__ int s[512];
    int v = (threadIdx.x < nb) ? bsum[threadIdx.x] : 0;
    s[threadIdx.x] = v;
    __syncthreads();
#pragma unroll
    for (int off = 1; off < 512; off <<= 1) {
        int t = (threadIdx.x >= off) ? s[threadIdx.x - off] : 0;
        __syncthreads();
        s[threadIdx.x] += t;
        __syncthreads();
    }
    if (threadIdx.x < nb) bsum[threadIdx.x] = s[threadIdx.x] - v;
}

__global__ void k_prep(int* __restrict__ offs, const int* __restrict__ bsum,
                       const int* __restrict__ deg, int* __restrict__ cursor,
                       float* __restrict__ inv, int n, int E) {
    int i = blockIdx.x * 256 + threadIdx.x;
    if (i >= n) return;
    int o = offs[i] + bsum[i >> 8];
    offs[i] = o;
    cursor[i] = o;
    inv[i] = 1.0f / fmaxf((float)deg[i], 1.0f);
    if (i == 0) offs[n] = E;
}

__global__ void k_fill(const int* __restrict__ src, const int* __restrict__ dst,
                       int* __restrict__ cursor, int* __restrict__ adj, int E) {
    int e = blockIdx.x * blockDim.x + threadIdx.x;
    if (e < E) {
        int pos = atomicAdd(&cursor[dst[e]], 1);
        adj[pos] = src[e];
    }
}

// ===========================================================================
// Gather-aggregate (mean): one 64-lane wave per node, lanes own channels.
// ===========================================================================
template <int D>
__global__ void k_gather(const float* __restrict__ h, const int* __restrict__ adj,
                         const int* __restrict__ offs, const float* __restrict__ inv,
                         float* __restrict__ mean, int n) {
    int node = (blockIdx.x * blockDim.x + threadIdx.x) >> 6;
    int lane = threadIdx.x & 63;
    if (node >= n) return;
    int beg = offs[node];
    int end = offs[node + 1];
    float iv = inv[node];
    constexpr int J = (D + 63) / 64;
    float acc[J];
#pragma unroll
    for (int j = 0; j < J; ++j) acc[j] = 0.0f;
    for (int p = beg; p < end; ++p) {
        int s = adj[p];  // wave-uniform -> broadcast
        const float* row = h + (size_t)s * D;
#pragma unroll
        for (int j = 0; j < J; ++j) {
            int c = lane + j * 64;
            if (D % 64 == 0 || c < D) acc[j] += row[c];
        }
    }
#pragma unroll
    for (int j = 0; j < J; ++j) {
        int c = lane + j * 64;
        if (D % 64 == 0 || c < D) mean[(size_t)node * D + c] = acc[j] * iv;
    }
}

// ===========================================================================
// Simple linear (layer 1: DIN=10, DOUT=64). mean already divided.
// ===========================================================================
template <int DIN, int DOUT, bool RELU>
__global__ void k_linear(const float* __restrict__ h, const float* __restrict__ mean,
                         const float* __restrict__ Wl, const float* __restrict__ Wr,
                         const float* __restrict__ bias,
                         const float* __restrict__ bn_g, const float* __restrict__ bn_b,
                         const float* __restrict__ bn_m, const float* __restrict__ bn_v,
                         float* __restrict__ out, int n) {
    int tid = blockIdx.x * blockDim.x + threadIdx.x;
    int node = tid / DOUT;
    int c = tid - node * DOUT;
    if (node >= n) return;

    const float* hr = h + (size_t)node * DIN;
    const float* mr = mean + (size_t)node * DIN;

    float acc = bias[c];
#pragma unroll
    for (int k = 0; k < DIN; ++k) {
        acc += mr[k] * Wl[k * DOUT + c] + hr[k] * Wr[k * DOUT + c];
    }
    float o = (acc - bn_m[c]) * rsqrtf(bn_v[c] + EPS_BN) * bn_g[c] + bn_b[c];
    if (RELU) o = fmaxf(o, 0.0f);
    out[(size_t)node * DOUT + c] = o;
}

// ===========================================================================
// Register-tiled linear+BN(+ReLU), DOUT=128. Block: 64 nodes x 128 c.
// K chunked (KC=64): LDS = 64 x 66 float2 = 33 KB -> 4 blocks/CU (16 waves).
// Row pad +2 float2 (16B-aligned): node-groups land 16 banks apart -> 2-way
// LDS aliasing, which is free on gfx950 (m136). Was 4-way = 1.58x.
// ===========================================================================
template <int DIN, bool RELU>
__global__ __launch_bounds__(256, 4) void k_linear_tiled(
    const float* __restrict__ h, const float* __restrict__ mean,
    const float* __restrict__ Wl, const float* __restrict__ Wr,
    const float* __restrict__ bias,
    const float* __restrict__ bn_g, const float* __restrict__ bn_b,
    const float* __restrict__ bn_m, const float* __restrict__ bn_v,
    float* __restrict__ out, int n) {
    constexpr int DOUT = 128;
    constexpr int KC = 64;
    static_assert(DIN % KC == 0, "DIN must be multiple of KC");
    __shared__ float2 tile[64][KC + 2];  // +2: keep 16B align, break conflicts

    const int tid = threadIdx.x;
    const int node0 = blockIdx.x * 64;

    const int cgrp = tid & 15;   // 16 c-groups of 8 channels
    const int ngrp = tid >> 4;   // 16 node-groups of 4 nodes
    const int c0 = cgrp * 8;
    const int nbase = ngrp * 4;

    float acc[4][8];
#pragma unroll
    for (int nn = 0; nn < 4; ++nn)
#pragma unroll
        for (int j = 0; j < 8; ++j) acc[nn][j] = 0.0f;

    for (int ch = 0; ch < DIN / KC; ++ch) {
        if (ch) __syncthreads();  // protect tile before overwrite
        // ---- stage chunk: tile[nd][kk] = {mean, h} ----
#pragma unroll
        for (int it = 0; it < (64 * KC / 4) / 256; ++it) {
            int qid = it * 256 + tid;
            int nd = qid >> 4;         // KC/4 == 16
            int kq = qid & 15;
            int gn = node0 + nd;
            if (gn > n - 1) gn = n - 1;
            size_t base = (size_t)gn * DIN + ch * KC + kq * 4;
            float4 hv = *(const float4*)&h[base];
            float4 mv = *(const float4*)&mean[base];
            float4* dstp = (float4*)&tile[nd][kq * 4];
            dstp[0] = {mv.x, hv.x, mv.y, hv.y};
            dstp[1] = {mv.z, hv.z, mv.w, hv.w};
        }
        __syncthreads();

#pragma unroll 4
        for (int kk = 0; kk < KC; ++kk) {
            int k = ch * KC + kk;
            float4 wl0 = *(const float4*)&Wl[k * DOUT + c0];
            float4 wl1 = *(const float4*)&Wl[k * DOUT + c0 + 4];
            float4 wr0 = *(const float4*)&Wr[k * DOUT + c0];
            float4 wr1 = *(const float4*)&Wr[k * DOUT + c0 + 4];
#pragma unroll
            for (int nn = 0; nn < 4; ++nn) {
                float2 mh = tile[nbase + nn][kk];
                acc[nn][0] = fmaf(mh.x, wl0.x, fmaf(mh.y, wr0.x, acc[nn][0]));
                acc[nn][1] = fmaf(mh.x, wl0.y, fmaf(mh.y, wr0.y, acc[nn][1]));
                acc[nn][2] = fmaf(mh.x, wl0.z, fmaf(mh.y, wr0.z, acc[nn][2]));
                acc[nn][3] = fmaf(mh.x, wl0.w, fmaf(mh.y, wr0.w, acc[nn][3]));
                acc[nn][4] = fmaf(mh.x, wl1.x, fmaf(mh.y, wr1.x, acc[nn][4]));
                acc[nn][5] = fmaf(mh.x, wl1.y, fmaf(mh.y, wr1.y, acc[nn][5]));
                acc[nn][6] = fmaf(mh.x, wl1.z, fmaf(mh.y, wr1.z, acc[nn][6]));
                acc[nn][7] = fmaf(mh.x, wl1.w, fmaf(mh.y, wr1.w, acc[nn][7]));
            }
        }
    }

    // ---- epilogue: BN(+ReLU), folded ----
    float A[8], C[8];
#pragma unroll
    for (int j = 0; j < 8; ++j) {
        int c = c0 + j;
        float a = bn_g[c] * rsqrtf(bn_v[c] + EPS_BN);
        A[j] = a;
        C[j] = (bias[c] - bn_m[c]) * a + bn_b[c];
    }
#pragma unroll
    for (int nn = 0; nn < 4; ++nn) {
        int gn = node0 + nbase + nn;
        if (gn >= n) continue;
        float4 o0, o1;
        o0.x = acc[nn][0] * A[0] + C[0];
        o0.y = acc[nn][1] * A[1] + C[1];
        o0.z = acc[nn][2] * A[2] + C[2];
        o0.w = acc[nn][3] * A[3] + C[3];
        o1.x = acc[nn][4] * A[4] + C[4];
        o1.y = acc[nn][5] * A[5] + C[5];
        o1.z = acc[nn][6] * A[6] + C[6];
        o1.w = acc[nn][7] * A[7] + C[7];
        if (RELU) {
            o0.x = fmaxf(o0.x, 0.0f); o0.y = fmaxf(o0.y, 0.0f);
            o0.z = fmaxf(o0.z, 0.0f); o0.w = fmaxf(o0.w, 0.0f);
            o1.x = fmaxf(o1.x, 0.0f); o1.y = fmaxf(o1.y, 0.0f);
            o1.z = fmaxf(o1.z, 0.0f); o1.w = fmaxf(o1.w, 0.0f);
        }
        *(float4*)&out[(size_t)gn * DOUT + c0] = o0;
        *(float4*)&out[(size_t)gn * DOUT + c0 + 4] = o1;
    }
}

// ===========================================================================
// L2-normalize + logits (one wave per node)
// ===========================================================================
__global__ void k_norm_logits(float* __restrict__ emb, float* __restrict__ logits,
                              const float* __restrict__ Wc, const float* __restrict__ bc,
                              int n) {
    int gtid = blockIdx.x * blockDim.x + threadIdx.x;
    int node = gtid >> 6;
    int lane = threadIdx.x & 63;
    if (node >= n) return;

    float* row = emb + (size_t)node * 128;
    float a = row[lane];
    float b = row[lane + 64];

    float ss = a * a + b * b;
#pragma unroll
    for (int off = 32; off; off >>= 1) ss += __shfl_down(ss, off, 64);
    ss = __shfl(ss, 0, 64);

    float inv = 1.0f / fmaxf(sqrtf(ss), EPS_NORM);
    a *= inv;
    b *= inv;
    row[lane] = a;
    row[lane + 64] = b;

    float l0 = a * Wc[lane * 2 + 0] + b * Wc[(lane + 64) * 2 + 0];
    float l1 = a * Wc[lane * 2 + 1] + b * Wc[(lane + 64) * 2 + 1];
#pragma unroll
    for (int off = 32; off; off >>= 1) {
        l0 += __shfl_down(l0, off, 64);
        l1 += __shfl_down(l1, off, 64);
    }
    if (lane == 0) {
        logits[(size_t)node * 2 + 0] = l0 + bc[0];
        logits[(size_t)node * 2 + 1] = l1 + bc[1];
    }
}

// ===========================================================================
extern "C" void kernel_launch(void* const* d_in, const int* in_sizes, int n_in,
                              void* d_out, int out_size, void* d_ws, size_t ws_size,
                              hipStream_t stream) {
    const float* x    = (const float*)d_in[0];
    const int*   ei   = (const int*)d_in[1];
    const int*   src  = ei;
    const int*   dstp = ei + N_EDGES;

    const float* W1l = (const float*)d_in[2];
    const float* W1r = (const float*)d_in[3];
    const float* b1  = (const float*)d_in[4];
    const float* g1  = (const float*)d_in[5];
    const float* bb1 = (const float*)d_in[6];
    const float* m1  = (const float*)d_in[7];
    const float* v1  = (const float*)d_in[8];

    const float* W2l = (const float*)d_in[9];
    const float* W2r = (const float*)d_in[10];
    const float* b2  = (const float*)d_in[11];
    const float* g2  = (const float*)d_in[12];
    const float* bb2 = (const float*)d_in[13];
    const float* m2  = (const float*)d_in[14];
    const float* v2  = (const float*)d_in[15];

    const float* W3l = (const float*)d_in[16];
    const float* W3r = (const float*)d_in[17];
    const float* b3  = (const float*)d_in[18];
    const float* g3  = (const float*)d_in[19];
    const float* bb3 = (const float*)d_in[20];
    const float* m3  = (const float*)d_in[21];
    const float* v3  = (const float*)d_in[22];

    const float* Wc = (const float*)d_in[23];
    const float* bc = (const float*)d_in[24];

    // workspace layout (all 4-byte elements)
    float* inv   = (float*)d_ws;                        // N
    int*   deg   = (int*)(inv + N_NODES);               // N
    int*   offs  = deg + N_NODES;                       // N+1
    int*   cursor= offs + N_NODES + 1;                  // N
    int*   adj   = cursor + N_NODES;                    // E
    int*   bsum  = adj + N_EDGES;                       // 512
    float* agg   = (float*)(bsum + 512);                // N*128 (mean buffer)
    float* h1    = agg + (size_t)N_NODES * 128;         // N*64
    float* h2    = h1 + (size_t)N_NODES * 64;           // N*128

    float* emb    = (float*)d_out;
    float* logits = emb + (size_t)N_NODES * 128;

    const int B = 256;
    const int nb = (N_NODES + 255) / 256;               // 391 <= 512
    const int nTileBlocks = (N_NODES + 63) / 64;
    const int nWaveBlocks = ((size_t)N_NODES * 64 + B - 1) / B;

    // ---- CSR build ----
    hipMemsetAsync(deg, 0, N_NODES * sizeof(int), stream);
    k_deg<<<(N_EDGES + B - 1) / B, B, 0, stream>>>(dstp, deg, N_EDGES);
    k_scan1<<<nb, 256, 0, stream>>>(deg, offs, bsum, N_NODES);
    k_scan2<<<1, 512, 0, stream>>>(bsum, nb);
    k_prep<<<nb, 256, 0, stream>>>(offs, bsum, deg, cursor, inv, N_NODES, N_EDGES);
    k_fill<<<(N_EDGES + B - 1) / B, B, 0, stream>>>(src, dstp, cursor, adj, N_EDGES);

    // ---- layer 1: 10 -> 64, ReLU ----
    k_gather<10><<<nWaveBlocks, B, 0, stream>>>(x, adj, offs, inv, agg, N_NODES);
    k_linear<10, 64, true><<<((size_t)N_NODES * 64 + B - 1) / B, B, 0, stream>>>(
        x, agg, W1l, W1r, b1, g1, bb1, m1, v1, h1, N_NODES);

    // ---- layer 2: 64 -> 128, ReLU ----
    k_gather<64><<<nWaveBlocks, B, 0, stream>>>(h1, adj, offs, inv, agg, N_NODES);
    k_linear_tiled<64, true><<<nTileBlocks, 256, 0, stream>>>(
        h1, agg, W2l, W2r, b2, g2, bb2, m2, v2, h2, N_NODES);

    // ---- layer 3: 128 -> 128, no ReLU, into d_out emb region ----
    k_gather<128><<<nWaveBlocks, B, 0, stream>>>(h2, adj, offs, inv, agg, N_NODES);
    k_linear_tiled<128, false><<<nTileBlocks, 256, 0, stream>>>(
        h2, agg, W3l, W3r, b3, g3, bb3, m3, v3, emb, N_NODES);

    // ---- normalize + logits ----
    k_norm_logits<<<nWaveBlocks, B, 0, stream>>>(emb, logits, Wc, bc, N_NODES);
}

// Round 5
// 581.487 us; speedup vs baseline: 3.3732x; 1.0816x over previous
//
#include <hip/hip_runtime.h>

#define N_NODES 100000
#define N_EDGES 600000
#define EPS_BN 1e-5f
#define EPS_NORM 1e-12f

// ===========================================================================
// CSR build: degree histogram -> exclusive scan -> cursor fill
// ===========================================================================
__global__ void k_deg(const int* __restrict__ dst, int* __restrict__ deg, int E) {
    int e = blockIdx.x * blockDim.x + threadIdx.x;
    if (e < E) atomicAdd(&deg[dst[e]], 1);
}

__global__ void k_scan1(const int* __restrict__ in, int* __restrict__ out,
                        int* __restrict__ bsum, int n) {
    __shared__ int s[256];
    int i = blockIdx.x * 256 + threadIdx.x;
    int v = (i < n) ? in[i] : 0;
    s[threadIdx.x] = v;
    __syncthreads();
#pragma unroll
    for (int off = 1; off < 256; off <<= 1) {
        int t = (threadIdx.x >= off) ? s[threadIdx.x - off] : 0;
        __syncthreads();
        s[threadIdx.x] += t;
        __syncthreads();
    }
    if (i < n) out[i] = s[threadIdx.x] - v;
    if (threadIdx.x == 255) bsum[blockIdx.x] = s[255];
}

__global__ void k_scan2(int* __restrict__ bsum, int nb) {
    __shared__ int s[512];
    int v = (threadIdx.x < nb) ? bsum[threadIdx.x] : 0;
    s[threadIdx.x] = v;
    __syncthreads();
#pragma unroll
    for (int off = 1; off < 512; off <<= 1) {
        int t = (threadIdx.x >= off) ? s[threadIdx.x - off] : 0;
        __syncthreads();
        s[threadIdx.x] += t;
        __syncthreads();
    }
    if (threadIdx.x < nb) bsum[threadIdx.x] = s[threadIdx.x] - v;
}

__global__ void k_prep(int* __restrict__ offs, const int* __restrict__ bsum,
                       const int* __restrict__ deg, int* __restrict__ cursor,
                       float* __restrict__ inv, int n, int E) {
    int i = blockIdx.x * 256 + threadIdx.x;
    if (i >= n) return;
    int o = offs[i] + bsum[i >> 8];
    offs[i] = o;
    cursor[i] = o;
    inv[i] = 1.0f / fmaxf((float)deg[i], 1.0f);
    if (i == 0) offs[n] = E;
}

__global__ void k_fill(const int* __restrict__ src, const int* __restrict__ dst,
                       int* __restrict__ cursor, int* __restrict__ adj, int E) {
    int e = blockIdx.x * blockDim.x + threadIdx.x;
    if (e < E) {
        int pos = atomicAdd(&cursor[dst[e]], 1);
        adj[pos] = src[e];
    }
}

// ===========================================================================
// Gather-aggregate (mean): one 64-lane wave per node.
// ===========================================================================
// D=10 (layer 1): lanes 0..9 own one channel each.
__global__ void k_gather10(const float* __restrict__ h, const int* __restrict__ adj,
                           const int* __restrict__ offs, const float* __restrict__ inv,
                           float* __restrict__ mean, int n) {
    int node = (blockIdx.x * blockDim.x + threadIdx.x) >> 6;
    int lane = threadIdx.x & 63;
    if (node >= n) return;
    int beg = offs[node], end = offs[node + 1];
    float iv = inv[node];
    float acc = 0.0f;
    for (int p = beg; p < end; ++p) {
        int s = adj[p];
        if (lane < 10) acc += h[(size_t)s * 10 + lane];
    }
    if (lane < 10) mean[(size_t)node * 10 + lane] = acc * iv;
}

// D=64: one b32 per edge per lane, unroll x2 for load ILP.
__global__ void k_gather64(const float* __restrict__ h, const int* __restrict__ adj,
                           const int* __restrict__ offs, const float* __restrict__ inv,
                           float* __restrict__ mean, int n) {
    int node = (blockIdx.x * blockDim.x + threadIdx.x) >> 6;
    int lane = threadIdx.x & 63;
    if (node >= n) return;
    int beg = offs[node], end = offs[node + 1];
    float iv = inv[node];
    float a0 = 0.0f, a1 = 0.0f;
    int p = beg;
    for (; p + 2 <= end; p += 2) {
        int s0 = adj[p], s1 = adj[p + 1];
        a0 += h[(size_t)s0 * 64 + lane];
        a1 += h[(size_t)s1 * 64 + lane];
    }
    if (p < end) a0 += h[(size_t)adj[p] * 64 + lane];
    mean[(size_t)node * 64 + lane] = (a0 + a1) * iv;
}

// D=128: float2 per lane (512B/instr coalesced), unroll x2.
__global__ void k_gather128(const float* __restrict__ h, const int* __restrict__ adj,
                            const int* __restrict__ offs, const float* __restrict__ inv,
                            float* __restrict__ mean, int n) {
    int node = (blockIdx.x * blockDim.x + threadIdx.x) >> 6;
    int lane = threadIdx.x & 63;
    if (node >= n) return;
    int beg = offs[node], end = offs[node + 1];
    float iv = inv[node];
    float2 a0 = {0.0f, 0.0f}, a1 = {0.0f, 0.0f};
    int p = beg;
    for (; p + 2 <= end; p += 2) {
        int s0 = adj[p], s1 = adj[p + 1];
        float2 v0 = *(const float2*)&h[(size_t)s0 * 128 + lane * 2];
        float2 v1 = *(const float2*)&h[(size_t)s1 * 128 + lane * 2];
        a0.x += v0.x; a0.y += v0.y;
        a1.x += v1.x; a1.y += v1.y;
    }
    if (p < end) {
        float2 v0 = *(const float2*)&h[(size_t)adj[p] * 128 + lane * 2];
        a0.x += v0.x; a0.y += v0.y;
    }
    float2 o = {(a0.x + a1.x) * iv, (a0.y + a1.y) * iv};
    *(float2*)&mean[(size_t)node * 128 + lane * 2] = o;
}

// ===========================================================================
// Simple linear (layer 1: DIN=10, DOUT=64). mean already divided.
// ===========================================================================
template <int DIN, int DOUT, bool RELU>
__global__ void k_linear(const float* __restrict__ h, const float* __restrict__ mean,
                         const float* __restrict__ Wl, const float* __restrict__ Wr,
                         const float* __restrict__ bias,
                         const float* __restrict__ bn_g, const float* __restrict__ bn_b,
                         const float* __restrict__ bn_m, const float* __restrict__ bn_v,
                         float* __restrict__ out, int n) {
    int tid = blockIdx.x * blockDim.x + threadIdx.x;
    int node = tid / DOUT;
    int c = tid - node * DOUT;
    if (node >= n) return;

    const float* hr = h + (size_t)node * DIN;
    const float* mr = mean + (size_t)node * DIN;

    float acc = bias[c];
#pragma unroll
    for (int k = 0; k < DIN; ++k) {
        acc += mr[k] * Wl[k * DOUT + c] + hr[k] * Wr[k * DOUT + c];
    }
    float o = (acc - bn_m[c]) * rsqrtf(bn_v[c] + EPS_BN) * bn_g[c] + bn_b[c];
    if (RELU) o = fmaxf(o, 0.0f);
    out[(size_t)node * DOUT + c] = o;
}

// ===========================================================================
// Register-tiled linear+BN(+ReLU), DOUT=128. Block: 128 nodes x 128 c,
// 256 threads, each thread 8 nodes x 8 channels (64 acc VGPRs) -> per k:
// 128 FMA vs 8 ds_read_b64 + 4 weight loads (2x arithmetic intensity of R4).
// KC=32: LDS = 128 x 33 float2 = 33 KB -> 4 blocks/CU. Row stride 33 float2:
// node-groups 8 rows apart land 16 banks apart -> 2-way (free, m136).
// ===========================================================================
template <int DIN, bool RELU>
__global__ __launch_bounds__(256, 4) void k_linear_tiled(
    const float* __restrict__ h, const float* __restrict__ mean,
    const float* __restrict__ Wl, const float* __restrict__ Wr,
    const float* __restrict__ bias,
    const float* __restrict__ bn_g, const float* __restrict__ bn_b,
    const float* __restrict__ bn_m, const float* __restrict__ bn_v,
    float* __restrict__ out, int n) {
    constexpr int DOUT = 128;
    constexpr int KC = 32;
    constexpr int NODES = 128;
    static_assert(DIN % KC == 0, "DIN must be multiple of KC");
    __shared__ float2 tile[NODES][KC + 1];  // stride 33: conflict-free reads

    const int tid = threadIdx.x;
    const int node0 = blockIdx.x * NODES;

    const int cgrp = tid & 15;   // 16 c-groups of 8 channels
    const int ngrp = tid >> 4;   // 16 node-groups of 8 nodes
    const int c0 = cgrp * 8;
    const int nbase = ngrp * 8;

    float acc[8][8];
#pragma unroll
    for (int nn = 0; nn < 8; ++nn)
#pragma unroll
        for (int j = 0; j < 8; ++j) acc[nn][j] = 0.0f;

    for (int ch = 0; ch < DIN / KC; ++ch) {
        if (ch) __syncthreads();
        // ---- stage chunk: tile[nd][kk] = {mean, h} ----
#pragma unroll
        for (int it = 0; it < 4; ++it) {
            int qid = it * 256 + tid;  // 0..1023
            int nd = qid >> 3;         // 0..127
            int kq = qid & 7;          // k = kq*4
            int gn = node0 + nd;
            if (gn > n - 1) gn = n - 1;
            size_t base = (size_t)gn * DIN + ch * KC + kq * 4;
            float4 hv = *(const float4*)&h[base];
            float4 mv = *(const float4*)&mean[base];
            float2* t = &tile[nd][kq * 4];
            t[0] = {mv.x, hv.x};
            t[1] = {mv.y, hv.y};
            t[2] = {mv.z, hv.z};
            t[3] = {mv.w, hv.w};
        }
        __syncthreads();

#pragma unroll 1
        for (int kk = 0; kk < KC; ++kk) {
            int k = ch * KC + kk;
            float4 wl0 = *(const float4*)&Wl[k * DOUT + c0];
            float4 wl1 = *(const float4*)&Wl[k * DOUT + c0 + 4];
            float4 wr0 = *(const float4*)&Wr[k * DOUT + c0];
            float4 wr1 = *(const float4*)&Wr[k * DOUT + c0 + 4];
#pragma unroll
            for (int nn = 0; nn < 8; ++nn) {
                float2 mh = tile[nbase + nn][kk];
                acc[nn][0] = fmaf(mh.x, wl0.x, fmaf(mh.y, wr0.x, acc[nn][0]));
                acc[nn][1] = fmaf(mh.x, wl0.y, fmaf(mh.y, wr0.y, acc[nn][1]));
                acc[nn][2] = fmaf(mh.x, wl0.z, fmaf(mh.y, wr0.z, acc[nn][2]));
                acc[nn][3] = fmaf(mh.x, wl0.w, fmaf(mh.y, wr0.w, acc[nn][3]));
                acc[nn][4] = fmaf(mh.x, wl1.x, fmaf(mh.y, wr1.x, acc[nn][4]));
                acc[nn][5] = fmaf(mh.x, wl1.y, fmaf(mh.y, wr1.y, acc[nn][5]));
                acc[nn][6] = fmaf(mh.x, wl1.z, fmaf(mh.y, wr1.z, acc[nn][6]));
                acc[nn][7] = fmaf(mh.x, wl1.w, fmaf(mh.y, wr1.w, acc[nn][7]));
            }
        }
    }

    // ---- epilogue: BN(+ReLU), folded ----
    float A[8], C[8];
#pragma unroll
    for (int j = 0; j < 8; ++j) {
        int c = c0 + j;
        float a = bn_g[c] * rsqrtf(bn_v[c] + EPS_BN);
        A[j] = a;
        C[j] = (bias[c] - bn_m[c]) * a + bn_b[c];
    }
#pragma unroll
    for (int nn = 0; nn < 8; ++nn) {
        int gn = node0 + nbase + nn;
        if (gn >= n) continue;
        float4 o0, o1;
        o0.x = acc[nn][0] * A[0] + C[0];
        o0.y = acc[nn][1] * A[1] + C[1];
        o0.z = acc[nn][2] * A[2] + C[2];
        o0.w = acc[nn][3] * A[3] + C[3];
        o1.x = acc[nn][4] * A[4] + C[4];
        o1.y = acc[nn][5] * A[5] + C[5];
        o1.z = acc[nn][6] * A[6] + C[6];
        o1.w = acc[nn][7] * A[7] + C[7];
        if (RELU) {
            o0.x = fmaxf(o0.x, 0.0f); o0.y = fmaxf(o0.y, 0.0f);
            o0.z = fmaxf(o0.z, 0.0f); o0.w = fmaxf(o0.w, 0.0f);
            o1.x = fmaxf(o1.x, 0.0f); o1.y = fmaxf(o1.y, 0.0f);
            o1.z = fmaxf(o1.z, 0.0f); o1.w = fmaxf(o1.w, 0.0f);
        }
        *(float4*)&out[(size_t)gn * DOUT + c0] = o0;
        *(float4*)&out[(size_t)gn * DOUT + c0 + 4] = o1;
    }
}

// ===========================================================================
// L2-normalize + logits (one wave per node)
// ===========================================================================
__global__ void k_norm_logits(float* __restrict__ emb, float* __restrict__ logits,
                              const float* __restrict__ Wc, const float* __restrict__ bc,
                              int n) {
    int gtid = blockIdx.x * blockDim.x + threadIdx.x;
    int node = gtid >> 6;
    int lane = threadIdx.x & 63;
    if (node >= n) return;

    float* row = emb + (size_t)node * 128;
    float a = row[lane];
    float b = row[lane + 64];

    float ss = a * a + b * b;
#pragma unroll
    for (int off = 32; off; off >>= 1) ss += __shfl_down(ss, off, 64);
    ss = __shfl(ss, 0, 64);

    float inv = 1.0f / fmaxf(sqrtf(ss), EPS_NORM);
    a *= inv;
    b *= inv;
    row[lane] = a;
    row[lane + 64] = b;

    float l0 = a * Wc[lane * 2 + 0] + b * Wc[(lane + 64) * 2 + 0];
    float l1 = a * Wc[lane * 2 + 1] + b * Wc[(lane + 64) * 2 + 1];
#pragma unroll
    for (int off = 32; off; off >>= 1) {
        l0 += __shfl_down(l0, off, 64);
        l1 += __shfl_down(l1, off, 64);
    }
    if (lane == 0) {
        logits[(size_t)node * 2 + 0] = l0 + bc[0];
        logits[(size_t)node * 2 + 1] = l1 + bc[1];
    }
}

// ===========================================================================
extern "C" void kernel_launch(void* const* d_in, const int* in_sizes, int n_in,
                              void* d_out, int out_size, void* d_ws, size_t ws_size,
                              hipStream_t stream) {
    const float* x    = (const float*)d_in[0];
    const int*   ei   = (const int*)d_in[1];
    const int*   src  = ei;
    const int*   dstp = ei + N_EDGES;

    const float* W1l = (const float*)d_in[2];
    const float* W1r = (const float*)d_in[3];
    const float* b1  = (const float*)d_in[4];
    const float* g1  = (const float*)d_in[5];
    const float* bb1 = (const float*)d_in[6];
    const float* m1  = (const float*)d_in[7];
    const float* v1  = (const float*)d_in[8];

    const float* W2l = (const float*)d_in[9];
    const float* W2r = (const float*)d_in[10];
    const float* b2  = (const float*)d_in[11];
    const float* g2  = (const float*)d_in[12];
    const float* bb2 = (const float*)d_in[13];
    const float* m2  = (const float*)d_in[14];
    const float* v2  = (const float*)d_in[15];

    const float* W3l = (const float*)d_in[16];
    const float* W3r = (const float*)d_in[17];
    const float* b3  = (const float*)d_in[18];
    const float* g3  = (const float*)d_in[19];
    const float* bb3 = (const float*)d_in[20];
    const float* m3  = (const float*)d_in[21];
    const float* v3  = (const float*)d_in[22];

    const float* Wc = (const float*)d_in[23];
    const float* bc = (const float*)d_in[24];

    // workspace layout (all 4-byte elements)
    float* inv   = (float*)d_ws;                        // N
    int*   deg   = (int*)(inv + N_NODES);               // N
    int*   offs  = deg + N_NODES;                       // N+1
    int*   cursor= offs + N_NODES + 1;                  // N
    int*   adj   = cursor + N_NODES;                    // E
    int*   bsum  = adj + N_EDGES;                       // 512
    float* agg   = (float*)(bsum + 512);                // N*128 (mean buffer)
    float* h1    = agg + (size_t)N_NODES * 128;         // N*64
    float* h2    = h1 + (size_t)N_NODES * 64;           // N*128

    float* emb    = (float*)d_out;
    float* logits = emb + (size_t)N_NODES * 128;

    const int B = 256;
    const int nb = (N_NODES + 255) / 256;               // 391 <= 512
    const int nTileBlocks = (N_NODES + 127) / 128;
    const int nWaveBlocks = ((size_t)N_NODES * 64 + B - 1) / B;

    // ---- CSR build ----
    hipMemsetAsync(deg, 0, N_NODES * sizeof(int), stream);
    k_deg<<<(N_EDGES + B - 1) / B, B, 0, stream>>>(dstp, deg, N_EDGES);
    k_scan1<<<nb, 256, 0, stream>>>(deg, offs, bsum, N_NODES);
    k_scan2<<<1, 512, 0, stream>>>(bsum, nb);
    k_prep<<<nb, 256, 0, stream>>>(offs, bsum, deg, cursor, inv, N_NODES, N_EDGES);
    k_fill<<<(N_EDGES + B - 1) / B, B, 0, stream>>>(src, dstp, cursor, adj, N_EDGES);

    // ---- layer 1: 10 -> 64, ReLU ----
    k_gather10<<<nWaveBlocks, B, 0, stream>>>(x, adj, offs, inv, agg, N_NODES);
    k_linear<10, 64, true><<<((size_t)N_NODES * 64 + B - 1) / B, B, 0, stream>>>(
        x, agg, W1l, W1r, b1, g1, bb1, m1, v1, h1, N_NODES);

    // ---- layer 2: 64 -> 128, ReLU ----
    k_gather64<<<nWaveBlocks, B, 0, stream>>>(h1, adj, offs, inv, agg, N_NODES);
    k_linear_tiled<64, true><<<nTileBlocks, 256, 0, stream>>>(
        h1, agg, W2l, W2r, b2, g2, bb2, m2, v2, h2, N_NODES);

    // ---- layer 3: 128 -> 128, no ReLU, into d_out emb region ----
    k_gather128<<<nWaveBlocks, B, 0, stream>>>(h2, adj, offs, inv, agg, N_NODES);
    k_linear_tiled<128, false><<<nTileBlocks, 256, 0, stream>>>(
        h2, agg, W3l, W3r, b3, g3, bb3, m3, v3, emb, N_NODES);

    // ---- normalize + logits ----
    k_norm_logits<<<nWaveBlocks, B, 0, stream>>>(emb, logits, Wc, bc, N_NODES);
}

// Round 6
// 574.770 us; speedup vs baseline: 3.4127x; 1.0117x over previous
//
#include <hip/hip_runtime.h>

#define N_NODES 100000
#define N_EDGES 600000
#define EPS_BN 1e-5f
#define EPS_NORM 1e-12f

// ===========================================================================
// CSR build: degree histogram -> exclusive scan -> cursor fill
// ===========================================================================
__global__ void k_deg(const int* __restrict__ dst, int* __restrict__ deg, int E) {
    int e = blockIdx.x * blockDim.x + threadIdx.x;
    if (e < E) atomicAdd(&deg[dst[e]], 1);
}

__global__ void k_scan1(const int* __restrict__ in, int* __restrict__ out,
                        int* __restrict__ bsum, int n) {
    __shared__ int s[256];
    int i = blockIdx.x * 256 + threadIdx.x;
    int v = (i < n) ? in[i] : 0;
    s[threadIdx.x] = v;
    __syncthreads();
#pragma unroll
    for (int off = 1; off < 256; off <<= 1) {
        int t = (threadIdx.x >= off) ? s[threadIdx.x - off] : 0;
        __syncthreads();
        s[threadIdx.x] += t;
        __syncthreads();
    }
    if (i < n) out[i] = s[threadIdx.x] - v;
    if (threadIdx.x == 255) bsum[blockIdx.x] = s[255];
}

__global__ void k_scan2(int* __restrict__ bsum, int nb) {
    __shared__ int s[512];
    int v = (threadIdx.x < nb) ? bsum[threadIdx.x] : 0;
    s[threadIdx.x] = v;
    __syncthreads();
#pragma unroll
    for (int off = 1; off < 512; off <<= 1) {
        int t = (threadIdx.x >= off) ? s[threadIdx.x - off] : 0;
        __syncthreads();
        s[threadIdx.x] += t;
        __syncthreads();
    }
    if (threadIdx.x < nb) bsum[threadIdx.x] = s[threadIdx.x] - v;
}

__global__ void k_prep(int* __restrict__ offs, const int* __restrict__ bsum,
                       const int* __restrict__ deg, int* __restrict__ cursor,
                       float* __restrict__ inv, int n, int E) {
    int i = blockIdx.x * 256 + threadIdx.x;
    if (i >= n) return;
    int o = offs[i] + bsum[i >> 8];
    offs[i] = o;
    cursor[i] = o;
    inv[i] = 1.0f / fmaxf((float)deg[i], 1.0f);
    if (i == 0) offs[n] = E;
}

__global__ void k_fill(const int* __restrict__ src, const int* __restrict__ dst,
                       int* __restrict__ cursor, int* __restrict__ adj, int E) {
    int e = blockIdx.x * blockDim.x + threadIdx.x;
    if (e < E) {
        int pos = atomicAdd(&cursor[dst[e]], 1);
        adj[pos] = src[e];
    }
}

// ===========================================================================
// Gather-aggregate (mean): one 64-lane wave per node.
// ===========================================================================
__global__ void k_gather10(const float* __restrict__ h, const int* __restrict__ adj,
                           const int* __restrict__ offs, const float* __restrict__ inv,
                           float* __restrict__ mean, int n) {
    int node = (blockIdx.x * blockDim.x + threadIdx.x) >> 6;
    int lane = threadIdx.x & 63;
    if (node >= n) return;
    int beg = offs[node], end = offs[node + 1];
    float iv = inv[node];
    float acc = 0.0f;
    for (int p = beg; p < end; ++p) {
        int s = adj[p];
        if (lane < 10) acc += h[(size_t)s * 10 + lane];
    }
    if (lane < 10) mean[(size_t)node * 10 + lane] = acc * iv;
}

__global__ void k_gather64(const float* __restrict__ h, const int* __restrict__ adj,
                           const int* __restrict__ offs, const float* __restrict__ inv,
                           float* __restrict__ mean, int n) {
    int node = (blockIdx.x * blockDim.x + threadIdx.x) >> 6;
    int lane = threadIdx.x & 63;
    if (node >= n) return;
    int beg = offs[node], end = offs[node + 1];
    float iv = inv[node];
    float a0 = 0.0f, a1 = 0.0f;
    int p = beg;
    for (; p + 2 <= end; p += 2) {
        int s0 = adj[p], s1 = adj[p + 1];
        a0 += h[(size_t)s0 * 64 + lane];
        a1 += h[(size_t)s1 * 64 + lane];
    }
    if (p < end) a0 += h[(size_t)adj[p] * 64 + lane];
    mean[(size_t)node * 64 + lane] = (a0 + a1) * iv;
}

__global__ void k_gather128(const float* __restrict__ h, const int* __restrict__ adj,
                            const int* __restrict__ offs, const float* __restrict__ inv,
                            float* __restrict__ mean, int n) {
    int node = (blockIdx.x * blockDim.x + threadIdx.x) >> 6;
    int lane = threadIdx.x & 63;
    if (node >= n) return;
    int beg = offs[node], end = offs[node + 1];
    float iv = inv[node];
    float2 a0 = {0.0f, 0.0f}, a1 = {0.0f, 0.0f};
    int p = beg;
    for (; p + 2 <= end; p += 2) {
        int s0 = adj[p], s1 = adj[p + 1];
        float2 v0 = *(const float2*)&h[(size_t)s0 * 128 + lane * 2];
        float2 v1 = *(const float2*)&h[(size_t)s1 * 128 + lane * 2];
        a0.x += v0.x; a0.y += v0.y;
        a1.x += v1.x; a1.y += v1.y;
    }
    if (p < end) {
        float2 v0 = *(const float2*)&h[(size_t)adj[p] * 128 + lane * 2];
        a0.x += v0.x; a0.y += v0.y;
    }
    float2 o = {(a0.x + a1.x) * iv, (a0.y + a1.y) * iv};
    *(float2*)&mean[(size_t)node * 128 + lane * 2] = o;
}

// ===========================================================================
// Simple linear (layer 1: DIN=10, DOUT=64). mean already divided.
// ===========================================================================
template <int DIN, int DOUT, bool RELU>
__global__ void k_linear(const float* __restrict__ h, const float* __restrict__ mean,
                         const float* __restrict__ Wl, const float* __restrict__ Wr,
                         const float* __restrict__ bias,
                         const float* __restrict__ bn_g, const float* __restrict__ bn_b,
                         const float* __restrict__ bn_m, const float* __restrict__ bn_v,
                         float* __restrict__ out, int n) {
    int tid = blockIdx.x * blockDim.x + threadIdx.x;
    int node = tid / DOUT;
    int c = tid - node * DOUT;
    if (node >= n) return;

    const float* hr = h + (size_t)node * DIN;
    const float* mr = mean + (size_t)node * DIN;

    float acc = bias[c];
#pragma unroll
    for (int k = 0; k < DIN; ++k) {
        acc += mr[k] * Wl[k * DOUT + c] + hr[k] * Wr[k * DOUT + c];
    }
    float o = (acc - bn_m[c]) * rsqrtf(bn_v[c] + EPS_BN) * bn_g[c] + bn_b[c];
    if (RELU) o = fmaxf(o, 0.0f);
    out[(size_t)node * DOUT + c] = o;
}

// ===========================================================================
// Scalar-weight tiled linear+BN(+ReLU), DOUT=128.
// Block: 64 nodes x 128 ch, 256 threads. lane <-> node; each wave owns a
// 32-channel band (c0 = wave*32, wave id forced into SGPR via readfirstlane)
// so weight loads are wave-uniform -> s_load into SGPRs; FMA = v_fmac(vacc,
// sW, vmh) with the single allowed SGPR operand. Per k-step per lane: only
// 2 ds_read_b32 (stride-33 rows -> (lane+kk)%32 banks = 2-way = free).
// KC=32: LDS = 2*64*33*4 = 16.9 KB -> 9 blocks/CU by LDS; grid 1563 -> ~6
// resident blocks = 24 waves/CU.
// ===========================================================================
template <int DIN, bool RELU>
__global__ __launch_bounds__(256) void k_linear_sc(
    const float* __restrict__ h, const float* __restrict__ mean,
    const float* __restrict__ Wl, const float* __restrict__ Wr,
    const float* __restrict__ bias,
    const float* __restrict__ bn_g, const float* __restrict__ bn_b,
    const float* __restrict__ bn_m, const float* __restrict__ bn_v,
    float* __restrict__ out, int n) {
    constexpr int DOUT = 128;
    constexpr int KC = 32;
    constexpr int NODES = 64;
    constexpr int STR = KC + 1;  // 33: conflict-free column reads
    static_assert(DIN % KC == 0, "DIN must be multiple of KC");
    __shared__ float sm[NODES * STR];
    __shared__ float sh[NODES * STR];

    const int tid = threadIdx.x;
    const int lane = tid & 63;
    const int node0 = blockIdx.x * NODES;
    const int node = node0 + lane;
    // force wave id scalar so weight/bn addresses are provably uniform
    const int wv = __builtin_amdgcn_readfirstlane(tid >> 6);
    const int c0 = wv * 32;

    float acc[32];
#pragma unroll
    for (int c = 0; c < 32; ++c) acc[c] = 0.0f;

    const int nd = tid >> 2;       // 0..63: staged row
    const int kq = (tid & 3) * 8;  // 8-float column group

    for (int ch = 0; ch < DIN / KC; ++ch) {
        if (ch) __syncthreads();
        // ---- stage 64 rows x KC cols of (mean, h) ----
        {
            int gn = node0 + nd;
            if (gn > n - 1) gn = n - 1;
            size_t base = (size_t)gn * DIN + ch * KC + kq;
            float4 m0 = *(const float4*)&mean[base];
            float4 m1 = *(const float4*)&mean[base + 4];
            float4 h0 = *(const float4*)&h[base];
            float4 h1 = *(const float4*)&h[base + 4];
            int o = nd * STR + kq;
            sm[o + 0] = m0.x; sm[o + 1] = m0.y; sm[o + 2] = m0.z; sm[o + 3] = m0.w;
            sm[o + 4] = m1.x; sm[o + 5] = m1.y; sm[o + 6] = m1.z; sm[o + 7] = m1.w;
            sh[o + 0] = h0.x; sh[o + 1] = h0.y; sh[o + 2] = h0.z; sh[o + 3] = h0.w;
            sh[o + 4] = h1.x; sh[o + 5] = h1.y; sh[o + 6] = h1.z; sh[o + 7] = h1.w;
        }
        __syncthreads();

#pragma unroll 1
        for (int kk = 0; kk < KC; ++kk) {
            float m = sm[lane * STR + kk];
            float hh = sh[lane * STR + kk];
            const float* wl = &Wl[(size_t)(ch * KC + kk) * DOUT + c0];
            const float* wr = &Wr[(size_t)(ch * KC + kk) * DOUT + c0];
#pragma unroll
            for (int c = 0; c < 32; ++c) {
                acc[c] = fmaf(m, wl[c], fmaf(hh, wr[c], acc[c]));
            }
        }
    }

    // ---- epilogue: bias+BN folded (params wave-uniform -> scalar loads) ----
    if (node < n) {
        float o[32];
#pragma unroll
        for (int c = 0; c < 32; ++c) {
            int cc = c0 + c;
            float A = bn_g[cc] * rsqrtf(bn_v[cc] + EPS_BN);
            float C = (bias[cc] - bn_m[cc]) * A + bn_b[cc];
            float v = acc[c] * A + C;
            if (RELU) v = fmaxf(v, 0.0f);
            o[c] = v;
        }
        float* op = &out[(size_t)node * DOUT + c0];
#pragma unroll
        for (int q = 0; q < 8; ++q) {
            *(float4*)&op[q * 4] = *(float4*)&o[q * 4];
        }
    }
}

// ===========================================================================
// L2-normalize + logits (one wave per node)
// ===========================================================================
__global__ void k_norm_logits(float* __restrict__ emb, float* __restrict__ logits,
                              const float* __restrict__ Wc, const float* __restrict__ bc,
                              int n) {
    int gtid = blockIdx.x * blockDim.x + threadIdx.x;
    int node = gtid >> 6;
    int lane = threadIdx.x & 63;
    if (node >= n) return;

    float* row = emb + (size_t)node * 128;
    float a = row[lane];
    float b = row[lane + 64];

    float ss = a * a + b * b;
#pragma unroll
    for (int off = 32; off; off >>= 1) ss += __shfl_down(ss, off, 64);
    ss = __shfl(ss, 0, 64);

    float inv = 1.0f / fmaxf(sqrtf(ss), EPS_NORM);
    a *= inv;
    b *= inv;
    row[lane] = a;
    row[lane + 64] = b;

    float l0 = a * Wc[lane * 2 + 0] + b * Wc[(lane + 64) * 2 + 0];
    float l1 = a * Wc[lane * 2 + 1] + b * Wc[(lane + 64) * 2 + 1];
#pragma unroll
    for (int off = 32; off; off >>= 1) {
        l0 += __shfl_down(l0, off, 64);
        l1 += __shfl_down(l1, off, 64);
    }
    if (lane == 0) {
        logits[(size_t)node * 2 + 0] = l0 + bc[0];
        logits[(size_t)node * 2 + 1] = l1 + bc[1];
    }
}

// ===========================================================================
extern "C" void kernel_launch(void* const* d_in, const int* in_sizes, int n_in,
                              void* d_out, int out_size, void* d_ws, size_t ws_size,
                              hipStream_t stream) {
    const float* x    = (const float*)d_in[0];
    const int*   ei   = (const int*)d_in[1];
    const int*   src  = ei;
    const int*   dstp = ei + N_EDGES;

    const float* W1l = (const float*)d_in[2];
    const float* W1r = (const float*)d_in[3];
    const float* b1  = (const float*)d_in[4];
    const float* g1  = (const float*)d_in[5];
    const float* bb1 = (const float*)d_in[6];
    const float* m1  = (const float*)d_in[7];
    const float* v1  = (const float*)d_in[8];

    const float* W2l = (const float*)d_in[9];
    const float* W2r = (const float*)d_in[10];
    const float* b2  = (const float*)d_in[11];
    const float* g2  = (const float*)d_in[12];
    const float* bb2 = (const float*)d_in[13];
    const float* m2  = (const float*)d_in[14];
    const float* v2  = (const float*)d_in[15];

    const float* W3l = (const float*)d_in[16];
    const float* W3r = (const float*)d_in[17];
    const float* b3  = (const float*)d_in[18];
    const float* g3  = (const float*)d_in[19];
    const float* bb3 = (const float*)d_in[20];
    const float* m3  = (const float*)d_in[21];
    const float* v3  = (const float*)d_in[22];

    const float* Wc = (const float*)d_in[23];
    const float* bc = (const float*)d_in[24];

    // workspace layout (all 4-byte elements)
    float* inv   = (float*)d_ws;                        // N
    int*   deg   = (int*)(inv + N_NODES);               // N
    int*   offs  = deg + N_NODES;                       // N+1
    int*   cursor= offs + N_NODES + 1;                  // N
    int*   adj   = cursor + N_NODES;                    // E
    int*   bsum  = adj + N_EDGES;                       // 512
    float* agg   = (float*)(bsum + 512);                // N*128 (mean buffer)
    float* h1    = agg + (size_t)N_NODES * 128;         // N*64
    float* h2    = h1 + (size_t)N_NODES * 64;           // N*128

    float* emb    = (float*)d_out;
    float* logits = emb + (size_t)N_NODES * 128;

    const int B = 256;
    const int nb = (N_NODES + 255) / 256;               // 391 <= 512
    const int nScBlocks = (N_NODES + 63) / 64;          // 1563
    const int nWaveBlocks = ((size_t)N_NODES * 64 + B - 1) / B;

    // ---- CSR build ----
    hipMemsetAsync(deg, 0, N_NODES * sizeof(int), stream);
    k_deg<<<(N_EDGES + B - 1) / B, B, 0, stream>>>(dstp, deg, N_EDGES);
    k_scan1<<<nb, 256, 0, stream>>>(deg, offs, bsum, N_NODES);
    k_scan2<<<1, 512, 0, stream>>>(bsum, nb);
    k_prep<<<nb, 256, 0, stream>>>(offs, bsum, deg, cursor, inv, N_NODES, N_EDGES);
    k_fill<<<(N_EDGES + B - 1) / B, B, 0, stream>>>(src, dstp, cursor, adj, N_EDGES);

    // ---- layer 1: 10 -> 64, ReLU ----
    k_gather10<<<nWaveBlocks, B, 0, stream>>>(x, adj, offs, inv, agg, N_NODES);
    k_linear<10, 64, true><<<((size_t)N_NODES * 64 + B - 1) / B, B, 0, stream>>>(
        x, agg, W1l, W1r, b1, g1, bb1, m1, v1, h1, N_NODES);

    // ---- layer 2: 64 -> 128, ReLU ----
    k_gather64<<<nWaveBlocks, B, 0, stream>>>(h1, adj, offs, inv, agg, N_NODES);
    k_linear_sc<64, true><<<nScBlocks, 256, 0, stream>>>(
        h1, agg, W2l, W2r, b2, g2, bb2, m2, v2, h2, N_NODES);

    // ---- layer 3: 128 -> 128, no ReLU, into d_out emb region ----
    k_gather128<<<nWaveBlocks, B, 0, stream>>>(h2, adj, offs, inv, agg, N_NODES);
    k_linear_sc<128, false><<<nScBlocks, 256, 0, stream>>>(
        h2, agg, W3l, W3r, b3, g3, bb3, m3, v3, emb, N_NODES);

    // ---- normalize + logits ----
    k_norm_logits<<<nWaveBlocks, B, 0, stream>>>(emb, logits, Wc, bc, N_NODES);
}